// Round 16
// baseline (579.401 us; speedup 1.0000x reference)
//
#include <hip/hip_runtime.h>
#include <math.h>

#define BATCH 512
#define NG 16
#define GSZ 32
#define H 128
#define E 64
#define PRE 512
#define BOT 1024
#define MLPD 1024
#define SEQ 12
#define AK 1152   // Abf row length = H + BOT

typedef __attribute__((ext_vector_type(8))) short bf16x8;
typedef __attribute__((ext_vector_type(4))) float f32x4;

union bf8pack { ushort s[8]; uint4 v; };

__device__ __forceinline__ unsigned short f2bf(float f) {
    unsigned u = __float_as_uint(f);
    u += 0x7FFF + ((u >> 16) & 1);   // round-to-nearest-even
    return (unsigned short)(u >> 16);
}

__device__ __forceinline__ uint4 pack8(const float* s) {
    float4 a = *(const float4*)s, b = *(const float4*)(s + 4);
    bf8pack o;
    o.s[0] = f2bf(a.x); o.s[1] = f2bf(a.y); o.s[2] = f2bf(a.z); o.s[3] = f2bf(a.w);
    o.s[4] = f2bf(b.x); o.s[5] = f2bf(b.y); o.s[6] = f2bf(b.z); o.s[7] = f2bf(b.w);
    return o.v;
}

#define GLB(p) ((const __attribute__((address_space(1))) unsigned int*)(p))
#define LDS(p) ((__attribute__((address_space(3))) unsigned int*)(p))

// ---------------------------------------------------------------- one-shot prep (R13, 8-wide)
#define U0 ((BOT * PRE) / 8)     /* W2pk   */
#define U1 ((MLPD * AK) / 8)     /* Wm1pk  */
#define U2 ((H * MLPD) / 8)      /* Wm2pk  */
#define U3 ((PRE * H) / 8)       /* W1pk   */
#define U4 (PRE)                 /* wc (scalar) */
#define U5 ((BATCH * H) / 4)     /* cbuf float4 copy */
#define U5b ((BATCH * H) / 8)    /* Ahpk pack of hh (t=0 gate-A) */
#define U6 (BATCH * 2)           /* pos (scalar) */
#define U7 ((512 * 128) / 8)     /* Whpk   */
#define U8 (512)                 /* Wx0/Wx1/bx */
#define PREP_TOT (U0 + U1 + U2 + U3 + U4 + U5 + U5b + U6 + U7 + U8 + 1)

__global__ void prep_kernel(
    const float* __restrict__ W2, const float* __restrict__ Wm1,
    const float* __restrict__ Wm2, const float* __restrict__ W1,
    const float* __restrict__ Wp, const float* __restrict__ bp, const float* __restrict__ b1,
    const float* __restrict__ ch, const float* __restrict__ hh, const float* __restrict__ last_pos,
    const float* __restrict__ Wih, const float* __restrict__ Whh,
    const float* __restrict__ bih, const float* __restrict__ bhh,
    const float* __restrict__ Wse, const float* __restrict__ bse,
    unsigned short* __restrict__ W2pk, unsigned short* __restrict__ Wm1pk,
    unsigned short* __restrict__ Wm2pk, unsigned short* __restrict__ W1pk,
    float* __restrict__ Wcx, float* __restrict__ Wcy, float* __restrict__ biash,
    float* __restrict__ cbuf, unsigned short* __restrict__ Ahpk, float* __restrict__ pos,
    unsigned short* __restrict__ Whpk,
    float* __restrict__ Wx0, float* __restrict__ Wx1, float* __restrict__ bx,
    float* __restrict__ loss)
{
    long idx = (long)blockIdx.x * 256 + threadIdx.x;
    if (idx < U0) {
        int u = (int)idx;
        int lane = u & 63, rest = u >> 6;
        int ksg = rest & 15, cg = rest >> 4;
        int col = cg * 16 + (lane & 15);
        int kk = ksg * 32 + (lane >> 4) * 8;
        *(uint4*)&W2pk[(size_t)u * 8] = pack8(&W2[(size_t)col * PRE + kk]);
        return;
    }
    idx -= U0;
    if (idx < U1) {
        int u = (int)idx;
        int lane = u & 63, rest = u >> 6;
        int ksg = rest % 36, cg = rest / 36;
        int col = cg * 16 + (lane & 15);
        int k = ksg * 32 + (lane >> 4) * 8;
        *(uint4*)&Wm1pk[(size_t)u * 8] = pack8(&Wm1[(size_t)col * AK + k]);
        return;
    }
    idx -= U1;
    if (idx < U2) {
        int u = (int)idx;
        int lane = u & 63, rest = u >> 6;
        int ksg = rest & 31, cg = rest >> 5;
        int col = cg * 16 + (lane & 15);
        int k = ksg * 32 + (lane >> 4) * 8;
        *(uint4*)&Wm2pk[(size_t)u * 8] = pack8(&Wm2[(size_t)col * MLPD + k]);
        return;
    }
    idx -= U2;
    if (idx < U3) {
        int u = (int)idx;
        int l16 = u & 15, quad = (u >> 4) & 3, nt = (u >> 6) & 3, ks = (u >> 8) & 3, w = u >> 10;
        int col = w * 64 + nt * 16 + l16;
        int k = ks * 32 + quad * 8;
        *(uint4*)&W1pk[(size_t)u * 8] = pack8(&W1[col * 192 + E + k]);
        return;
    }
    idx -= U3;
    if (idx < U4) {
        int p = (int)idx;
        float sx = 0.f, sy = 0.f, sb = 0.f;
#pragma unroll 8
        for (int e = 0; e < E; ++e) {
            float w = W1[p * 192 + e];
            sx += w * Wp[e * 2 + 0];
            sy += w * Wp[e * 2 + 1];
            sb += w * bp[e];
        }
        Wcx[p] = sx; Wcy[p] = sy; biash[p] = b1[p] + sb;
        return;
    }
    idx -= U4;
    if (idx < U5) { ((float4*)cbuf)[idx] = ((const float4*)ch)[idx]; return; }
    idx -= U5;
    if (idx < U5b) {
        int u = (int)idx;
        int lane = u & 63, rest = u >> 6;
        int ks = rest & 3, rowtile = rest >> 2;
        int row = rowtile * 16 + (lane & 15);
        int k = ks * 32 + (lane >> 4) * 8;
        *(uint4*)&Ahpk[(size_t)u * 8] = pack8(&hh[(size_t)row * H + k]);
        return;
    }
    idx -= U5b;
    if (idx < U6) { pos[idx] = last_pos[idx]; return; }
    idx -= U6;
    if (idx < U7) {
        int u = (int)idx;
        int l16 = u & 15, quad = (u >> 4) & 3, ks = (u >> 6) & 3, w = (u >> 8) & 7, g = u >> 11;
        int col = g * 128 + w * 16 + l16;
        int k = ks * 32 + quad * 8;
        *(uint4*)&Whpk[(size_t)u * 8] = pack8(&Whh[(size_t)col * H + k]);
        return;
    }
    idx -= U7;
    if (idx < U8) {
        int u = (int)idx;
        float sx = 0.f, sy = 0.f, sb = 0.f;
#pragma unroll 8
        for (int e = 0; e < E; ++e) {
            float w = Wih[u * E + e];
            sx += w * Wse[e * 2 + 0];
            sy += w * Wse[e * 2 + 1];
            sb += w * bse[e];
        }
        Wx0[u] = sx; Wx1[u] = sy; bx[u] = sb + bih[u] + bhh[u];
        return;
    }
    idx -= U8;
    if (idx == 0) *loss = 0.0f;
}

// ---------------------------------------------------------------- lstm body (shared)
__device__ __forceinline__ void lstm_body(
    int s, int r0, int tid, int lane, int w, int quad, int l16,
    unsigned short* hmb /*gate-A in LDS*/, unsigned short* hnb, float* hnf, float* lred,
    const float* relin, const float* gt,
    const unsigned short* Whpk,
    const float* Wx0, const float* Wx1, const float* bx,
    const float* Wpos, const float* bpos,
    const unsigned short* W1pk, const float* biash,
    float* cbuf, unsigned short* Abf, float* Hpartf,
    float* pos, float* traj, float* loss)
{
    constexpr int LDHB = 136;
    constexpr int LDHF = 129;

    // ---- gate GEMM (K=128): A from LDS hmb ----
    f32x4 acc[4];
#pragma unroll
    for (int g4 = 0; g4 < 4; ++g4) acc[g4] = (f32x4)0.f;
#pragma unroll
    for (int ks = 0; ks < 4; ++ks) {
        bf16x8 af = *(const bf16x8*)&hmb[l16 * LDHB + ks * 32 + quad * 8];
#pragma unroll
        for (int gate = 0; gate < 4; ++gate) {
            bf16x8 bf = *(const bf16x8*)&Whpk[((size_t)((gate * 8 + w) * 4 + ks) * 64 + lane) * 8];
            acc[gate] = __builtin_amdgcn_mfma_f32_16x16x32_bf16(af, bf, acc[gate], 0, 0, 0);
        }
    }

    // ---- nonlinearity + c update ----
    {
        int u = w * 16 + l16;
        float wx0[4], wx1[4], bxv[4];
#pragma unroll
        for (int gate = 0; gate < 4; ++gate) {
            int col = gate * 128 + u;
            wx0[gate] = Wx0[col]; wx1[gate] = Wx1[col]; bxv[gate] = bx[col];
        }
#pragma unroll
        for (int r = 0; r < 4; ++r) {
            int row = quad * 4 + r;
            int b = r0 + row;
            float rx = relin[b * 2 + 0], ry = relin[b * 2 + 1];
            float i_ = acc[0][r] + rx * wx0[0] + ry * wx1[0] + bxv[0];
            float f_ = acc[1][r] + rx * wx0[1] + ry * wx1[1] + bxv[1];
            float g_ = acc[2][r] + rx * wx0[2] + ry * wx1[2] + bxv[2];
            float o_ = acc[3][r] + rx * wx0[3] + ry * wx1[3] + bxv[3];
            float ig = 1.0f / (1.0f + expf(-i_));
            float fg = 1.0f / (1.0f + expf(-f_));
            float gg = tanhf(g_);
            float og = 1.0f / (1.0f + expf(-o_));
            float c = fg * cbuf[(size_t)b * H + u] + ig * gg;
            cbuf[(size_t)b * H + u] = c;
            float h = og * tanhf(c);
            hnb[row * LDHB + u] = f2bf(h);
            hnf[row * LDHF + u] = h;
            Abf[(size_t)b * AK + u] = f2bf(h);
        }
    }
    __syncthreads();

    // ---- Hpart GEMM (dead at last step) ----
    if (s < SEQ - 1) {
        f32x4 acc2[4];
#pragma unroll
        for (int nt = 0; nt < 4; ++nt) acc2[nt] = (f32x4)0.f;
#pragma unroll
        for (int ks = 0; ks < 4; ++ks) {
            bf16x8 af = *(const bf16x8*)&hnb[l16 * LDHB + ks * 32 + quad * 8];
#pragma unroll
            for (int nt = 0; nt < 4; ++nt) {
                bf16x8 bfr = *(const bf16x8*)&W1pk[((size_t)((w * 4 + ks) * 4 + nt) * 64 + lane) * 8];
                acc2[nt] = __builtin_amdgcn_mfma_f32_16x16x32_bf16(af, bfr, acc2[nt], 0, 0, 0);
            }
        }
#pragma unroll
        for (int nt = 0; nt < 4; ++nt) {
            int col = w * 64 + nt * 16 + l16;
            float bv = biash[col];
#pragma unroll
            for (int r = 0; r < 4; ++r) {
                int row = quad * 4 + r;
                Hpartf[(size_t)(r0 + row) * PRE + col] = acc2[nt][r] + bv;
            }
        }
    }

    // ---- rel_pos / curr_pos / traj / loss ----
    {
        int row = tid >> 5, o = (tid >> 4) & 1, seg = tid & 15;
        const float* wr = Wpos + o * H + seg * 8;
        const float* hr = &hnf[row * LDHF + seg * 8];
        float acc3 = 0.f;
#pragma unroll
        for (int k = 0; k < 8; ++k) acc3 += wr[k] * hr[k];
        acc3 += __shfl_xor(acc3, 1);
        acc3 += __shfl_xor(acc3, 2);
        acc3 += __shfl_xor(acc3, 4);
        acc3 += __shfl_xor(acc3, 8);
        acc3 += bpos[o];
        int b = r0 + row;
        float d = acc3 - gt[b * 2 + o];
        if (seg == 0) {
            float lp = pos[b * 2 + o];
            pos[b * 2 + o] = acc3 + lp;
            traj[b * 2 + o] = acc3;
        }
        float part = (seg == 0) ? d * d : 0.f;
        part += __shfl_xor(part, 16);
        part += __shfl_xor(part, 32);
        if (lane == 0) lred[w] = part;
        __syncthreads();
        if (tid == 0) {
            float s2 = 0.f;
#pragma unroll
            for (int i = 0; i < 8; ++i) s2 += lred[i];
            atomicAdd(loss, s2 * (1.0f / 1024.0f));
        }
    }
}

// ---------------------------------------------------------------- standalone LSTM (t=0 only)
#define LROWS 16
__global__ __launch_bounds__(512) void lstm_hpart(
    const float* __restrict__ relin, const float* __restrict__ gt,
    const unsigned short* __restrict__ Whpk,
    const float* __restrict__ Wx0, const float* __restrict__ Wx1, const float* __restrict__ bx,
    const float* __restrict__ Wpos, const float* __restrict__ bpos,
    const unsigned short* __restrict__ W1pk, const float* __restrict__ biash,
    const unsigned short* __restrict__ Ahpk, float* __restrict__ cbuf,
    unsigned short* __restrict__ Abf, float* __restrict__ Hpartf,
    float* __restrict__ pos, float* __restrict__ traj, float* __restrict__ loss)
{
    constexpr int LDHB = 136;
    constexpr int LDHF = 129;
    __shared__ __align__(16) unsigned short hmb[LROWS * LDHB];
    __shared__ __align__(16) unsigned short hnb[LROWS * LDHB];
    __shared__ float hnf[LROWS * LDHF];
    __shared__ float lred[8];
    const int blk = blockIdx.x, tid = threadIdx.x;
    const int lane = tid & 63, w = tid >> 6;
    const int quad = lane >> 4, l16 = lane & 15;

    for (int e2 = tid; e2 < LROWS * H / 8; e2 += 512) {
        int lane2 = e2 & 63, ks = e2 >> 6;
        int row = lane2 & 15, k = ks * 32 + (lane2 >> 4) * 8;
        *(uint4*)&hmb[row * LDHB + k] = *(const uint4*)&Ahpk[((size_t)(blk * 4 + ks) * 64 + lane2) * 8];
    }
    __syncthreads();

    lstm_body(0, blk * LROWS, tid, lane, w, quad, l16, hmb, hnb, hnf, lred,
              relin, gt, Whpk, Wx0, Wx1, bx, Wpos, bpos, W1pk, biash,
              cbuf, Abf, Hpartf, pos, traj, loss);
}

// ---------------------------------------------------------------- fused MLP2 + LSTM(s)
// R16: phase-A K-loop accumulator splitting — 4 independent accumulators over
// K-quarters (chain depth 32 -> 8, ILP 4), final (a0+a1)+(a2+a3). Only f32 sum
// order changes (same partial structure as the old 4-way split-K mlp2).
__global__ __launch_bounds__(512) void mlp2_lstm(
    int s,
    const unsigned short* __restrict__ dhpk,
    const unsigned short* __restrict__ Wm2pk, const float* __restrict__ bm2,
    const float* __restrict__ relin, const float* __restrict__ gt,
    const unsigned short* __restrict__ Whpk,
    const float* __restrict__ Wx0, const float* __restrict__ Wx1, const float* __restrict__ bx,
    const float* __restrict__ Wpos, const float* __restrict__ bpos,
    const unsigned short* __restrict__ W1pk, const float* __restrict__ biash,
    float* __restrict__ cbuf,
    unsigned short* __restrict__ Abf, float* __restrict__ Hpartf,
    float* __restrict__ pos, float* __restrict__ traj, float* __restrict__ loss)
{
    constexpr int LDHB = 136;
    constexpr int LDHF = 129;
    __shared__ __align__(16) unsigned short hmb[LROWS * LDHB];
    __shared__ __align__(16) unsigned short hnb[LROWS * LDHB];
    __shared__ float hnf[LROWS * LDHF];
    __shared__ float lred[8];
    const int blk = blockIdx.x, tid = threadIdx.x;
    const int lane = tid & 63, w = tid >> 6;
    const int quad = lane >> 4, l16 = lane & 15;

    // ---- phase A: mlp2 — wave w owns cols w*16..w*16+16, K=1024, 4 acc chains ----
    f32x4 a0 = (f32x4)0.f, a1 = (f32x4)0.f, a2 = (f32x4)0.f, a3 = (f32x4)0.f;
#pragma unroll
    for (int j = 0; j < 8; ++j) {
        bf16x8 af0 = *(const bf16x8*)&dhpk[((size_t)(blk * 32 + j) * 64 + lane) * 8];
        bf16x8 bf0 = *(const bf16x8*)&Wm2pk[((size_t)(w * 32 + j) * 64 + lane) * 8];
        a0 = __builtin_amdgcn_mfma_f32_16x16x32_bf16(af0, bf0, a0, 0, 0, 0);
        bf16x8 af1 = *(const bf16x8*)&dhpk[((size_t)(blk * 32 + 8 + j) * 64 + lane) * 8];
        bf16x8 bf1 = *(const bf16x8*)&Wm2pk[((size_t)(w * 32 + 8 + j) * 64 + lane) * 8];
        a1 = __builtin_amdgcn_mfma_f32_16x16x32_bf16(af1, bf1, a1, 0, 0, 0);
        bf16x8 af2 = *(const bf16x8*)&dhpk[((size_t)(blk * 32 + 16 + j) * 64 + lane) * 8];
        bf16x8 bf2 = *(const bf16x8*)&Wm2pk[((size_t)(w * 32 + 16 + j) * 64 + lane) * 8];
        a2 = __builtin_amdgcn_mfma_f32_16x16x32_bf16(af2, bf2, a2, 0, 0, 0);
        bf16x8 af3 = *(const bf16x8*)&dhpk[((size_t)(blk * 32 + 24 + j) * 64 + lane) * 8];
        bf16x8 bf3 = *(const bf16x8*)&Wm2pk[((size_t)(w * 32 + 24 + j) * 64 + lane) * 8];
        a3 = __builtin_amdgcn_mfma_f32_16x16x32_bf16(af3, bf3, a3, 0, 0, 0);
    }
    {
        int u = w * 16 + l16;
        float bv = bm2[u];
#pragma unroll
        for (int r = 0; r < 4; ++r) {
            float v = (a0[r] + a1[r]) + (a2[r] + a3[r]);
            hmb[(quad * 4 + r) * LDHB + u] = f2bf(fmaxf(v + bv, 0.f));
        }
    }
    __syncthreads();

    lstm_body(s, blk * LROWS, tid, lane, w, quad, l16, hmb, hnb, hnf, lred,
              relin, gt, Whpk, Wx0, Wx1, bx, Wpos, bpos, W1pk, biash,
              cbuf, Abf, Hpartf, pos, traj, loss);
}

// ---------------------------------------------------------------- split-K bf16 MFMA GEMM, packed-B (R12 dbuf, R15 pad)
// MODE 1: Cb row-major bf16 | MODE 2: Cf row-major f32 | MODE 3: Cb fragment-packed
template <int BM, int BN, int KW, int NW, int MODE>
__global__ __launch_bounds__(256) void gemm_splitk_pk(
    const unsigned short* __restrict__ A, int lda,
    const unsigned short* __restrict__ Bpk, int K,
    const float* __restrict__ bias,
    float* __restrict__ Cf, unsigned short* __restrict__ Cb, int ldc)
{
    constexpr int MT = BM / 16;
    constexpr int NT = BN / (16 * NW);
    constexpr int ABUF = KW * BM * 64;
    constexpr int BNP = BN + 1;
    __shared__ __align__(16) unsigned short As[2 * ABUF];
    __shared__ float red[KW * BM * BNP];
    int tid = threadIdx.x;
    int lane = tid & 63, w = tid >> 6;
    int kslice = w / NW, nslice = w % NW;
    int gtid = tid & (NW * 64 - 1);
    int quad = lane >> 4, l16 = lane & 15;
    int m0 = blockIdx.y * BM, n0 = blockIdx.x * BN;
    const int KC = K / KW;
    const int NK = KC / 64;
    const int KSGT = K >> 5;
    const int cgbase = (n0 + nslice * (BN / NW)) >> 4;

    auto STAGE = [&](int ki, int bo) {
        int kb = kslice * KC + ki * 64;
#pragma unroll
        for (int u = 0; u < BM / (8 * NW); ++u) {
            int c = u * NW * 64 + gtid;
            __builtin_amdgcn_global_load_lds(
                GLB(A + (size_t)(m0 + (c >> 3)) * lda + kb + (c & 7) * 8),
                LDS(&As[bo + kslice * BM * 64 + c * 8]), 16, 0, 0);
        }
    };

    f32x4 acc[MT][NT];
#pragma unroll
    for (int mt = 0; mt < MT; ++mt)
#pragma unroll
        for (int nt = 0; nt < NT; ++nt) acc[mt][nt] = (f32x4)0.f;

    STAGE(0, 0);
    for (int ki = 0; ki < NK; ++ki) {
        int bo = (ki & 1) * ABUF;
        int kgbase = (kslice * KC + ki * 64) >> 5;
        __syncthreads();
#pragma unroll
        for (int ks = 0; ks < 2; ++ks) {
            bf16x8 af[MT], bfr[NT];
#pragma unroll
            for (int mt = 0; mt < MT; ++mt)
                af[mt] = *(const bf16x8*)&As[bo + kslice * BM * 64 + (mt * 16 + l16) * 64 + ks * 32 + quad * 8];
#pragma unroll
            for (int nt = 0; nt < NT; ++nt)
                bfr[nt] = *(const bf16x8*)&Bpk[((size_t)((cgbase + nt) * KSGT + kgbase + ks) * 64 + lane) * 8];
#pragma unroll
            for (int mt = 0; mt < MT; ++mt)
#pragma unroll
                for (int nt = 0; nt < NT; ++nt)
                    acc[mt][nt] = __builtin_amdgcn_mfma_f32_16x16x32_bf16(af[mt], bfr[nt], acc[mt][nt], 0, 0, 0);
        }
        if (ki + 1 < NK) STAGE(ki + 1, ((ki + 1) & 1) * ABUF);
    }

#pragma unroll
    for (int mt = 0; mt < MT; ++mt)
#pragma unroll
    for (int nt = 0; nt < NT; ++nt) {
#pragma unroll
        for (int r = 0; r < 4; ++r) {
            int row = mt * 16 + quad * 4 + r;
            int col = nslice * (BN / NW) + nt * 16 + l16;
            red[kslice * BM * BNP + row * BNP + col] = acc[mt][nt][r];
        }
    }
    __syncthreads();

#pragma unroll
    for (int o = 0; o < BM * BN / 256; ++o) {
        int e = o * 256 + tid;
        int row = e / BN, col = e % BN;
        float s = 0.f;
#pragma unroll
        for (int k = 0; k < KW; ++k) s += red[k * BM * BNP + row * BNP + col];
        float v = fmaxf(s + bias[n0 + col], 0.f);
        if (MODE == 1) {
            Cb[(size_t)(m0 + row) * ldc + n0 + col] = f2bf(v);
        } else if (MODE == 2) {
            Cf[(size_t)(m0 + row) * ldc + n0 + col] = v;
        } else {
            int gr = m0 + row, gc = n0 + col;
            int rowtile = gr >> 4, l16p = gr & 15;
            int ksv = gc >> 5, quadp = (gc >> 3) & 3, ep = gc & 7;
            int lanep = quadp * 16 + l16p;
            Cb[((size_t)(rowtile * (ldc >> 5) + ksv) * 64 + lanep) * 8 + ep] = f2bf(v);
        }
    }
}

// ---------------------------------------------------------------- fused x1-build + pool GEMM + max_j (R15 M-split)
__global__ __launch_bounds__(512) void pool_fused(
    const float* __restrict__ Hpartf, const float* __restrict__ pos,
    const float* __restrict__ Wcx, const float* __restrict__ Wcy,
    const unsigned short* __restrict__ W2pk,
    const float* __restrict__ b2, unsigned short* __restrict__ Abf)
{
    constexpr int LDA = 72;
    constexpr int ASZ = 64 * LDA;
    __shared__ __align__(16) unsigned short As[2 * ASZ];
    const int tid = threadIdx.x;
    const int lane = tid & 63, w = tid >> 6;
    const int quad = lane >> 4, l16 = lane & 15;
    const int n_tile = blockIdx.x, m_tile2 = blockIdx.y;
    const int g = m_tile2 >> 4, iq2 = m_tile2 & 15;
    const int n0 = n_tile * 512;

    const int brow = tid >> 3;
    const int k8 = (tid & 7) * 8;
    const int bi = iq2 * 2 + (brow >> 5), bj = brow & 31;
    const float rx = pos[(g * GSZ + bj) * 2 + 0] - pos[(g * GSZ + bi) * 2 + 0];
    const float ry = pos[(g * GSZ + bj) * 2 + 1] - pos[(g * GSZ + bi) * 2 + 1];
    const float* hrow = &Hpartf[(size_t)(g * GSZ + bj) * PRE];

    auto BUILD = [&](int k0i, unsigned short* dst) {
        const int k0 = k0i * 64;
        const float* hp = hrow + k0 + k8;
        const float* wx = Wcx + k0 + k8;
        const float* wy = Wcy + k0 + k8;
        float4 ha = *(const float4*)hp, hb = *(const float4*)(hp + 4);
        float4 xa = *(const float4*)wx, xb = *(const float4*)(wx + 4);
        float4 ya = *(const float4*)wy, yb = *(const float4*)(wy + 4);
        bf8pack o;
        o.s[0] = f2bf(fmaxf(ha.x + rx * xa.x + ry * ya.x, 0.f));
        o.s[1] = f2bf(fmaxf(ha.y + rx * xa.y + ry * ya.y, 0.f));
        o.s[2] = f2bf(fmaxf(ha.z + rx * xa.z + ry * ya.z, 0.f));
        o.s[3] = f2bf(fmaxf(ha.w + rx * xa.w + ry * ya.w, 0.f));
        o.s[4] = f2bf(fmaxf(hb.x + rx * xb.x + ry * yb.x, 0.f));
        o.s[5] = f2bf(fmaxf(hb.y + rx * xb.y + ry * yb.y, 0.f));
        o.s[6] = f2bf(fmaxf(hb.z + rx * xb.z + ry * yb.z, 0.f));
        o.s[7] = f2bf(fmaxf(hb.w + rx * xb.w + ry * yb.w, 0.f));
        *(uint4*)&dst[brow * LDA + k8] = o.v;
    };

    f32x4 acc[4][4];
#pragma unroll
    for (int mt = 0; mt < 4; ++mt)
#pragma unroll
        for (int nt = 0; nt < 4; ++nt) acc[mt][nt] = (f32x4)0.f;

    BUILD(0, As);
    for (int k0i = 0; k0i < 8; ++k0i) {
        unsigned short* cur = As + (k0i & 1) * ASZ;
        __syncthreads();
        __builtin_amdgcn_s_setprio(1);
#pragma unroll
        for (int ks = 0; ks < 2; ++ks) {
            bf16x8 bfr[4];
#pragma unroll
            for (int nt = 0; nt < 4; ++nt) {
                int cg = n_tile * 32 + w * 4 + nt;
                int ksg = k0i * 2 + ks;
                bfr[nt] = *(const bf16x8*)&W2pk[((size_t)(cg * 16 + ksg) * 64 + lane) * 8];
            }
#pragma unroll
            for (int mt = 0; mt < 4; ++mt) {
                bf16x8 af = *(const bf16x8*)&cur[(mt * 16 + l16) * LDA + ks * 32 + quad * 8];
#pragma unroll
                for (int nt = 0; nt < 4; ++nt)
                    acc[mt][nt] = __builtin_amdgcn_mfma_f32_16x16x32_bf16(af, bfr[nt], acc[mt][nt], 0, 0, 0);
            }
        }
        __builtin_amdgcn_s_setprio(0);
        if (k0i < 7) BUILD(k0i + 1, As + ((k0i + 1) & 1) * ASZ);
    }

#pragma unroll
    for (int il = 0; il < 2; ++il)
#pragma unroll
    for (int nt = 0; nt < 4; ++nt) {
        float u = -1e30f;
#pragma unroll
        for (int p = 0; p < 2; ++p)
#pragma unroll
            for (int r = 0; r < 4; ++r) u = fmaxf(u, acc[il * 2 + p][nt][r]);
        u = fmaxf(u, __shfl_xor(u, 16));
        u = fmaxf(u, __shfl_xor(u, 32));
        if (lane < 16) {
            int col = n0 + w * 64 + nt * 16 + l16;
            int gu = m_tile2 * 2 + il;
            Abf[(size_t)gu * AK + H + col] = f2bf(fmaxf(u + b2[col], 0.f));
        }
    }
}

// ---------------------------------------------------------------- launch
extern "C" void kernel_launch(void* const* d_in, const int* in_sizes, int n_in,
                              void* d_out, int out_size, void* d_ws, size_t ws_size,
                              hipStream_t stream)
{
    const float* last_pos     = (const float*)d_in[0];
    const float* last_pos_rel = (const float*)d_in[1];
    const float* hh           = (const float*)d_in[2];
    const float* ch           = (const float*)d_in[3];
    const float* ptr_rel      = (const float*)d_in[4];
    const float* Wih  = (const float*)d_in[6];
    const float* Whh  = (const float*)d_in[7];
    const float* bih  = (const float*)d_in[8];
    const float* bhh  = (const float*)d_in[9];
    const float* Wse  = (const float*)d_in[10];
    const float* bse  = (const float*)d_in[11];
    const float* Wpos = (const float*)d_in[12];
    const float* bpos = (const float*)d_in[13];
    const float* Wp   = (const float*)d_in[14];
    const float* bp   = (const float*)d_in[15];
    const float* W1   = (const float*)d_in[16];
    const float* b1   = (const float*)d_in[17];
    const float* W2   = (const float*)d_in[18];
    const float* b2   = (const float*)d_in[19];
    const float* Wm1  = (const float*)d_in[20];
    const float* bm1  = (const float*)d_in[21];
    const float* Wm2  = (const float*)d_in[22];
    const float* bm2  = (const float*)d_in[23];

    float* ws     = (float*)d_ws;
    unsigned short* Ahpk = (unsigned short*)ws;  // 128KB (t=0 gate-A)
    float* cbuf   = ws + BATCH * H;           // 65536
    float* pos    = cbuf + BATCH * H;         // 1024 (padded)
    float* Hpartf = pos + 1024;               // 262144
    float* Wcx    = Hpartf + BATCH * PRE;     // 512
    float* Wcy    = Wcx + PRE;                // 512
    float* biash  = Wcy + PRE;                // 512
    float* bx     = biash + PRE;              // 512
    float* Wx0    = bx + 512;                 // 512
    float* Wx1    = Wx0 + 512;                // 512
    unsigned short* ub    = (unsigned short*)(Wx1 + 512);
    unsigned short* Abf   = ub;                         // 512*1152
    unsigned short* dhpk  = Abf + (size_t)BATCH * AK;   // 512*1024 (fragment-packed)
    unsigned short* W2pk  = dhpk + (size_t)BATCH * MLPD;
    unsigned short* Wm1pk = W2pk + (size_t)BOT * PRE;
    unsigned short* Wm2pk = Wm1pk + (size_t)MLPD * AK;
    unsigned short* W1pk  = Wm2pk + (size_t)H * MLPD;   // 512*128 (packed)
    unsigned short* Whpk  = W1pk + (size_t)PRE * H;     // 512*128 (packed)

    float* out  = (float*)d_out;
    float* loss = out + SEQ * BATCH * 2;

    prep_kernel<<<(PREP_TOT + 255) / 256, 256, 0, stream>>>(
        W2, Wm1, Wm2, W1, Wp, bp, b1, ch, hh, last_pos, Wih, Whh, bih, bhh, Wse, bse,
        W2pk, Wm1pk, Wm2pk, W1pk, Wcx, Wcy, biash, cbuf, Ahpk, pos, Whpk, Wx0, Wx1, bx, loss);

    // step 0 LSTM (gate-A from prep-packed hh)
    lstm_hpart<<<BATCH / LROWS, 512, 0, stream>>>(
        last_pos_rel, ptr_rel, Whpk, Wx0, Wx1, bx, Wpos, bpos, W1pk, biash,
        Ahpk, cbuf, Abf, Hpartf, pos, out, loss);

    for (int t = 0; t < SEQ - 1; t++) {
        // pool(t): fused x1-build + GEMM + max_j — M-split, 512 blocks, 2/CU
        pool_fused<<<dim3(2, 256), 512, 0, stream>>>(Hpartf, pos, Wcx, Wcy, W2pk, b2, Abf);
        // mlp1(t): dh -> fragment-packed dhpk — R16: BM=32, 512 blocks, 2/CU
        gemm_splitk_pk<32, 32, 2, 2, 3><<<dim3(MLPD / 32, BATCH / 32), 256, 0, stream>>>(
            Abf, AK, Wm1pk, AK, bm1, nullptr, dhpk, MLPD);
        // mlp2(t) + lstm(t+1) fused — R16: 4-acc phase A (chain 32 -> 8)
        mlp2_lstm<<<BATCH / LROWS, 512, 0, stream>>>(
            t + 1, dhpk, Wm2pk, bm2,
            ptr_rel + t * BATCH * 2, ptr_rel + (t + 1) * BATCH * 2,
            Whpk, Wx0, Wx1, bx, Wpos, bpos, W1pk, biash,
            cbuf, Abf, Hpartf, pos, out + (t + 1) * BATCH * 2, loss);
    }
}

// Round 17
// 576.139 us; speedup vs baseline: 1.0057x; 1.0057x over previous
//
#include <hip/hip_runtime.h>
#include <math.h>

#define BATCH 512
#define NG 16
#define GSZ 32
#define H 128
#define E 64
#define PRE 512
#define BOT 1024
#define MLPD 1024
#define SEQ 12
#define AK 1152   // Abf row length = H + BOT

typedef __attribute__((ext_vector_type(8))) short bf16x8;
typedef __attribute__((ext_vector_type(4))) float f32x4;

union bf8pack { ushort s[8]; uint4 v; };

__device__ __forceinline__ unsigned short f2bf(float f) {
    unsigned u = __float_as_uint(f);
    u += 0x7FFF + ((u >> 16) & 1);   // round-to-nearest-even
    return (unsigned short)(u >> 16);
}

__device__ __forceinline__ uint4 pack8(const float* s) {
    float4 a = *(const float4*)s, b = *(const float4*)(s + 4);
    bf8pack o;
    o.s[0] = f2bf(a.x); o.s[1] = f2bf(a.y); o.s[2] = f2bf(a.z); o.s[3] = f2bf(a.w);
    o.s[4] = f2bf(b.x); o.s[5] = f2bf(b.y); o.s[6] = f2bf(b.z); o.s[7] = f2bf(b.w);
    return o.v;
}

#define GLB(p) ((const __attribute__((address_space(1))) unsigned int*)(p))
#define LDS(p) ((__attribute__((address_space(3))) unsigned int*)(p))

// ---------------------------------------------------------------- one-shot prep (R13, 8-wide)
#define U0 ((BOT * PRE) / 8)     /* W2pk   */
#define U1 ((MLPD * AK) / 8)     /* Wm1pk  */
#define U2 ((H * MLPD) / 8)      /* Wm2pk  */
#define U3 ((PRE * H) / 8)       /* W1pk   */
#define U4 (PRE)                 /* wc (scalar) */
#define U5 ((BATCH * H) / 4)     /* cbuf float4 copy */
#define U5b ((BATCH * H) / 8)    /* Ahpk pack of hh (t=0 gate-A) */
#define U6 (BATCH * 2)           /* pos (scalar) */
#define U7 ((512 * 128) / 8)     /* Whpk   */
#define U8 (512)                 /* Wx0/Wx1/bx */
#define PREP_TOT (U0 + U1 + U2 + U3 + U4 + U5 + U5b + U6 + U7 + U8 + 1)

__global__ void prep_kernel(
    const float* __restrict__ W2, const float* __restrict__ Wm1,
    const float* __restrict__ Wm2, const float* __restrict__ W1,
    const float* __restrict__ Wp, const float* __restrict__ bp, const float* __restrict__ b1,
    const float* __restrict__ ch, const float* __restrict__ hh, const float* __restrict__ last_pos,
    const float* __restrict__ Wih, const float* __restrict__ Whh,
    const float* __restrict__ bih, const float* __restrict__ bhh,
    const float* __restrict__ Wse, const float* __restrict__ bse,
    unsigned short* __restrict__ W2pk, unsigned short* __restrict__ Wm1pk,
    unsigned short* __restrict__ Wm2pk, unsigned short* __restrict__ W1pk,
    float* __restrict__ Wcx, float* __restrict__ Wcy, float* __restrict__ biash,
    float* __restrict__ cbuf, unsigned short* __restrict__ Ahpk, float* __restrict__ pos,
    unsigned short* __restrict__ Whpk,
    float* __restrict__ Wx0, float* __restrict__ Wx1, float* __restrict__ bx,
    float* __restrict__ loss)
{
    long idx = (long)blockIdx.x * 256 + threadIdx.x;
    if (idx < U0) {
        int u = (int)idx;
        int lane = u & 63, rest = u >> 6;
        int ksg = rest & 15, cg = rest >> 4;
        int col = cg * 16 + (lane & 15);
        int kk = ksg * 32 + (lane >> 4) * 8;
        *(uint4*)&W2pk[(size_t)u * 8] = pack8(&W2[(size_t)col * PRE + kk]);
        return;
    }
    idx -= U0;
    if (idx < U1) {
        int u = (int)idx;
        int lane = u & 63, rest = u >> 6;
        int ksg = rest % 36, cg = rest / 36;
        int col = cg * 16 + (lane & 15);
        int k = ksg * 32 + (lane >> 4) * 8;
        *(uint4*)&Wm1pk[(size_t)u * 8] = pack8(&Wm1[(size_t)col * AK + k]);
        return;
    }
    idx -= U1;
    if (idx < U2) {
        int u = (int)idx;
        int lane = u & 63, rest = u >> 6;
        int ksg = rest & 31, cg = rest >> 5;
        int col = cg * 16 + (lane & 15);
        int k = ksg * 32 + (lane >> 4) * 8;
        *(uint4*)&Wm2pk[(size_t)u * 8] = pack8(&Wm2[(size_t)col * MLPD + k]);
        return;
    }
    idx -= U2;
    if (idx < U3) {
        int u = (int)idx;
        int l16 = u & 15, quad = (u >> 4) & 3, nt = (u >> 6) & 3, ks = (u >> 8) & 3, w = u >> 10;
        int col = w * 64 + nt * 16 + l16;
        int k = ks * 32 + quad * 8;
        *(uint4*)&W1pk[(size_t)u * 8] = pack8(&W1[col * 192 + E + k]);
        return;
    }
    idx -= U3;
    if (idx < U4) {
        int p = (int)idx;
        float sx = 0.f, sy = 0.f, sb = 0.f;
#pragma unroll 8
        for (int e = 0; e < E; ++e) {
            float w = W1[p * 192 + e];
            sx += w * Wp[e * 2 + 0];
            sy += w * Wp[e * 2 + 1];
            sb += w * bp[e];
        }
        Wcx[p] = sx; Wcy[p] = sy; biash[p] = b1[p] + sb;
        return;
    }
    idx -= U4;
    if (idx < U5) { ((float4*)cbuf)[idx] = ((const float4*)ch)[idx]; return; }
    idx -= U5;
    if (idx < U5b) {
        int u = (int)idx;
        int lane = u & 63, rest = u >> 6;
        int ks = rest & 3, rowtile = rest >> 2;
        int row = rowtile * 16 + (lane & 15);
        int k = ks * 32 + (lane >> 4) * 8;
        *(uint4*)&Ahpk[(size_t)u * 8] = pack8(&hh[(size_t)row * H + k]);
        return;
    }
    idx -= U5b;
    if (idx < U6) { pos[idx] = last_pos[idx]; return; }
    idx -= U6;
    if (idx < U7) {
        int u = (int)idx;
        int l16 = u & 15, quad = (u >> 4) & 3, ks = (u >> 6) & 3, w = (u >> 8) & 7, g = u >> 11;
        int col = g * 128 + w * 16 + l16;
        int k = ks * 32 + quad * 8;
        *(uint4*)&Whpk[(size_t)u * 8] = pack8(&Whh[(size_t)col * H + k]);
        return;
    }
    idx -= U7;
    if (idx < U8) {
        int u = (int)idx;
        float sx = 0.f, sy = 0.f, sb = 0.f;
#pragma unroll 8
        for (int e = 0; e < E; ++e) {
            float w = Wih[u * E + e];
            sx += w * Wse[e * 2 + 0];
            sy += w * Wse[e * 2 + 1];
            sb += w * bse[e];
        }
        Wx0[u] = sx; Wx1[u] = sy; bx[u] = sb + bih[u] + bhh[u];
        return;
    }
    idx -= U8;
    if (idx == 0) *loss = 0.0f;
}

// ---------------------------------------------------------------- lstm body (shared)
__device__ __forceinline__ void lstm_body(
    int s, int r0, int tid, int lane, int w, int quad, int l16,
    unsigned short* hmb /*gate-A in LDS*/, unsigned short* hnb, float* hnf, float* lred,
    const float* relin, const float* gt,
    const unsigned short* Whpk,
    const float* Wx0, const float* Wx1, const float* bx,
    const float* Wpos, const float* bpos,
    const unsigned short* W1pk, const float* biash,
    float* cbuf, unsigned short* Abf, float* Hpartf,
    float* pos, float* traj, float* loss)
{
    constexpr int LDHB = 136;
    constexpr int LDHF = 129;

    // ---- gate GEMM (K=128): A from LDS hmb ----
    f32x4 acc[4];
#pragma unroll
    for (int g4 = 0; g4 < 4; ++g4) acc[g4] = (f32x4)0.f;
#pragma unroll
    for (int ks = 0; ks < 4; ++ks) {
        bf16x8 af = *(const bf16x8*)&hmb[l16 * LDHB + ks * 32 + quad * 8];
#pragma unroll
        for (int gate = 0; gate < 4; ++gate) {
            bf16x8 bf = *(const bf16x8*)&Whpk[((size_t)((gate * 8 + w) * 4 + ks) * 64 + lane) * 8];
            acc[gate] = __builtin_amdgcn_mfma_f32_16x16x32_bf16(af, bf, acc[gate], 0, 0, 0);
        }
    }

    // ---- nonlinearity + c update ----
    {
        int u = w * 16 + l16;
        float wx0[4], wx1[4], bxv[4];
#pragma unroll
        for (int gate = 0; gate < 4; ++gate) {
            int col = gate * 128 + u;
            wx0[gate] = Wx0[col]; wx1[gate] = Wx1[col]; bxv[gate] = bx[col];
        }
#pragma unroll
        for (int r = 0; r < 4; ++r) {
            int row = quad * 4 + r;
            int b = r0 + row;
            float rx = relin[b * 2 + 0], ry = relin[b * 2 + 1];
            float i_ = acc[0][r] + rx * wx0[0] + ry * wx1[0] + bxv[0];
            float f_ = acc[1][r] + rx * wx0[1] + ry * wx1[1] + bxv[1];
            float g_ = acc[2][r] + rx * wx0[2] + ry * wx1[2] + bxv[2];
            float o_ = acc[3][r] + rx * wx0[3] + ry * wx1[3] + bxv[3];
            float ig = 1.0f / (1.0f + expf(-i_));
            float fg = 1.0f / (1.0f + expf(-f_));
            float gg = tanhf(g_);
            float og = 1.0f / (1.0f + expf(-o_));
            float c = fg * cbuf[(size_t)b * H + u] + ig * gg;
            cbuf[(size_t)b * H + u] = c;
            float h = og * tanhf(c);
            hnb[row * LDHB + u] = f2bf(h);
            hnf[row * LDHF + u] = h;
            Abf[(size_t)b * AK + u] = f2bf(h);
        }
    }
    __syncthreads();

    // ---- Hpart GEMM (dead at last step) ----
    if (s < SEQ - 1) {
        f32x4 acc2[4];
#pragma unroll
        for (int nt = 0; nt < 4; ++nt) acc2[nt] = (f32x4)0.f;
#pragma unroll
        for (int ks = 0; ks < 4; ++ks) {
            bf16x8 af = *(const bf16x8*)&hnb[l16 * LDHB + ks * 32 + quad * 8];
#pragma unroll
            for (int nt = 0; nt < 4; ++nt) {
                bf16x8 bfr = *(const bf16x8*)&W1pk[((size_t)((w * 4 + ks) * 4 + nt) * 64 + lane) * 8];
                acc2[nt] = __builtin_amdgcn_mfma_f32_16x16x32_bf16(af, bfr, acc2[nt], 0, 0, 0);
            }
        }
#pragma unroll
        for (int nt = 0; nt < 4; ++nt) {
            int col = w * 64 + nt * 16 + l16;
            float bv = biash[col];
#pragma unroll
            for (int r = 0; r < 4; ++r) {
                int row = quad * 4 + r;
                Hpartf[(size_t)(r0 + row) * PRE + col] = acc2[nt][r] + bv;
            }
        }
    }

    // ---- rel_pos / curr_pos / traj / loss ----
    {
        int row = tid >> 5, o = (tid >> 4) & 1, seg = tid & 15;
        const float* wr = Wpos + o * H + seg * 8;
        const float* hr = &hnf[row * LDHF + seg * 8];
        float acc3 = 0.f;
#pragma unroll
        for (int k = 0; k < 8; ++k) acc3 += wr[k] * hr[k];
        acc3 += __shfl_xor(acc3, 1);
        acc3 += __shfl_xor(acc3, 2);
        acc3 += __shfl_xor(acc3, 4);
        acc3 += __shfl_xor(acc3, 8);
        acc3 += bpos[o];
        int b = r0 + row;
        float d = acc3 - gt[b * 2 + o];
        if (seg == 0) {
            float lp = pos[b * 2 + o];
            pos[b * 2 + o] = acc3 + lp;
            traj[b * 2 + o] = acc3;
        }
        float part = (seg == 0) ? d * d : 0.f;
        part += __shfl_xor(part, 16);
        part += __shfl_xor(part, 32);
        if (lane == 0) lred[w] = part;
        __syncthreads();
        if (tid == 0) {
            float s2 = 0.f;
#pragma unroll
            for (int i = 0; i < 8; ++i) s2 += lred[i];
            atomicAdd(loss, s2 * (1.0f / 1024.0f));
        }
    }
}

// ---------------------------------------------------------------- standalone LSTM (t=0 only)
#define LROWS 16
__global__ __launch_bounds__(512) void lstm_hpart(
    const float* __restrict__ relin, const float* __restrict__ gt,
    const unsigned short* __restrict__ Whpk,
    const float* __restrict__ Wx0, const float* __restrict__ Wx1, const float* __restrict__ bx,
    const float* __restrict__ Wpos, const float* __restrict__ bpos,
    const unsigned short* __restrict__ W1pk, const float* __restrict__ biash,
    const unsigned short* __restrict__ Ahpk, float* __restrict__ cbuf,
    unsigned short* __restrict__ Abf, float* __restrict__ Hpartf,
    float* __restrict__ pos, float* __restrict__ traj, float* __restrict__ loss)
{
    constexpr int LDHB = 136;
    constexpr int LDHF = 129;
    __shared__ __align__(16) unsigned short hmb[LROWS * LDHB];
    __shared__ __align__(16) unsigned short hnb[LROWS * LDHB];
    __shared__ float hnf[LROWS * LDHF];
    __shared__ float lred[8];
    const int blk = blockIdx.x, tid = threadIdx.x;
    const int lane = tid & 63, w = tid >> 6;
    const int quad = lane >> 4, l16 = lane & 15;

    for (int e2 = tid; e2 < LROWS * H / 8; e2 += 512) {
        int lane2 = e2 & 63, ks = e2 >> 6;
        int row = lane2 & 15, k = ks * 32 + (lane2 >> 4) * 8;
        *(uint4*)&hmb[row * LDHB + k] = *(const uint4*)&Ahpk[((size_t)(blk * 4 + ks) * 64 + lane2) * 8];
    }
    __syncthreads();

    lstm_body(0, blk * LROWS, tid, lane, w, quad, l16, hmb, hnb, hnf, lred,
              relin, gt, Whpk, Wx0, Wx1, bx, Wpos, bpos, W1pk, biash,
              cbuf, Abf, Hpartf, pos, traj, loss);
}

// ---------------------------------------------------------------- fused MLP2 + LSTM(s) (R14; R17 reverts R16's 4-acc)
__global__ __launch_bounds__(512) void mlp2_lstm(
    int s,
    const unsigned short* __restrict__ dhpk,
    const unsigned short* __restrict__ Wm2pk, const float* __restrict__ bm2,
    const float* __restrict__ relin, const float* __restrict__ gt,
    const unsigned short* __restrict__ Whpk,
    const float* __restrict__ Wx0, const float* __restrict__ Wx1, const float* __restrict__ bx,
    const float* __restrict__ Wpos, const float* __restrict__ bpos,
    const unsigned short* __restrict__ W1pk, const float* __restrict__ biash,
    float* __restrict__ cbuf,
    unsigned short* __restrict__ Abf, float* __restrict__ Hpartf,
    float* __restrict__ pos, float* __restrict__ traj, float* __restrict__ loss)
{
    constexpr int LDHB = 136;
    constexpr int LDHF = 129;
    __shared__ __align__(16) unsigned short hmb[LROWS * LDHB];
    __shared__ __align__(16) unsigned short hnb[LROWS * LDHB];
    __shared__ float hnf[LROWS * LDHF];
    __shared__ float lred[8];
    const int blk = blockIdx.x, tid = threadIdx.x;
    const int lane = tid & 63, w = tid >> 6;
    const int quad = lane >> 4, l16 = lane & 15;

    // ---- phase A: mlp2 — wave w owns cols w*16..w*16+16, K=1024 ----
    f32x4 acc0 = (f32x4)0.f;
#pragma unroll 8
    for (int ki = 0; ki < 32; ++ki) {
        bf16x8 af = *(const bf16x8*)&dhpk[((size_t)(blk * 32 + ki) * 64 + lane) * 8];
        bf16x8 bf = *(const bf16x8*)&Wm2pk[((size_t)(w * 32 + ki) * 64 + lane) * 8];
        acc0 = __builtin_amdgcn_mfma_f32_16x16x32_bf16(af, bf, acc0, 0, 0, 0);
    }
    {
        int u = w * 16 + l16;
        float bv = bm2[u];
#pragma unroll
        for (int r = 0; r < 4; ++r)
            hmb[(quad * 4 + r) * LDHB + u] = f2bf(fmaxf(acc0[r] + bv, 0.f));
    }
    __syncthreads();

    lstm_body(s, blk * LROWS, tid, lane, w, quad, l16, hmb, hnb, hnf, lred,
              relin, gt, Whpk, Wx0, Wx1, bx, Wpos, bpos, W1pk, biash,
              cbuf, Abf, Hpartf, pos, traj, loss);
}

// ---------------------------------------------------------------- split-K bf16 MFMA GEMM, packed-B (R12 dbuf, R15 pad)
// MODE 1: Cb row-major bf16 | MODE 2: Cf row-major f32 | MODE 3: Cb fragment-packed
template <int BM, int BN, int KW, int NW, int MODE>
__global__ __launch_bounds__(256) void gemm_splitk_pk(
    const unsigned short* __restrict__ A, int lda,
    const unsigned short* __restrict__ Bpk, int K,
    const float* __restrict__ bias,
    float* __restrict__ Cf, unsigned short* __restrict__ Cb, int ldc)
{
    constexpr int MT = BM / 16;
    constexpr int NT = BN / (16 * NW);
    constexpr int ABUF = KW * BM * 64;
    constexpr int BNP = BN + 1;
    __shared__ __align__(16) unsigned short As[2 * ABUF];
    __shared__ float red[KW * BM * BNP];
    int tid = threadIdx.x;
    int lane = tid & 63, w = tid >> 6;
    int kslice = w / NW, nslice = w % NW;
    int gtid = tid & (NW * 64 - 1);
    int quad = lane >> 4, l16 = lane & 15;
    int m0 = blockIdx.y * BM, n0 = blockIdx.x * BN;
    const int KC = K / KW;
    const int NK = KC / 64;
    const int KSGT = K >> 5;
    const int cgbase = (n0 + nslice * (BN / NW)) >> 4;

    auto STAGE = [&](int ki, int bo) {
        int kb = kslice * KC + ki * 64;
#pragma unroll
        for (int u = 0; u < BM / (8 * NW); ++u) {
            int c = u * NW * 64 + gtid;
            __builtin_amdgcn_global_load_lds(
                GLB(A + (size_t)(m0 + (c >> 3)) * lda + kb + (c & 7) * 8),
                LDS(&As[bo + kslice * BM * 64 + c * 8]), 16, 0, 0);
        }
    };

    f32x4 acc[MT][NT];
#pragma unroll
    for (int mt = 0; mt < MT; ++mt)
#pragma unroll
        for (int nt = 0; nt < NT; ++nt) acc[mt][nt] = (f32x4)0.f;

    STAGE(0, 0);
    for (int ki = 0; ki < NK; ++ki) {
        int bo = (ki & 1) * ABUF;
        int kgbase = (kslice * KC + ki * 64) >> 5;
        __syncthreads();
#pragma unroll
        for (int ks = 0; ks < 2; ++ks) {
            bf16x8 af[MT], bfr[NT];
#pragma unroll
            for (int mt = 0; mt < MT; ++mt)
                af[mt] = *(const bf16x8*)&As[bo + kslice * BM * 64 + (mt * 16 + l16) * 64 + ks * 32 + quad * 8];
#pragma unroll
            for (int nt = 0; nt < NT; ++nt)
                bfr[nt] = *(const bf16x8*)&Bpk[((size_t)((cgbase + nt) * KSGT + kgbase + ks) * 64 + lane) * 8];
#pragma unroll
            for (int mt = 0; mt < MT; ++mt)
#pragma unroll
                for (int nt = 0; nt < NT; ++nt)
                    acc[mt][nt] = __builtin_amdgcn_mfma_f32_16x16x32_bf16(af[mt], bfr[nt], acc[mt][nt], 0, 0, 0);
        }
        if (ki + 1 < NK) STAGE(ki + 1, ((ki + 1) & 1) * ABUF);
    }

#pragma unroll
    for (int mt = 0; mt < MT; ++mt)
#pragma unroll
    for (int nt = 0; nt < NT; ++nt) {
#pragma unroll
        for (int r = 0; r < 4; ++r) {
            int row = mt * 16 + quad * 4 + r;
            int col = nslice * (BN / NW) + nt * 16 + l16;
            red[kslice * BM * BNP + row * BNP + col] = acc[mt][nt][r];
        }
    }
    __syncthreads();

#pragma unroll
    for (int o = 0; o < BM * BN / 256; ++o) {
        int e = o * 256 + tid;
        int row = e / BN, col = e % BN;
        float s = 0.f;
#pragma unroll
        for (int k = 0; k < KW; ++k) s += red[k * BM * BNP + row * BNP + col];
        float v = fmaxf(s + bias[n0 + col], 0.f);
        if (MODE == 1) {
            Cb[(size_t)(m0 + row) * ldc + n0 + col] = f2bf(v);
        } else if (MODE == 2) {
            Cf[(size_t)(m0 + row) * ldc + n0 + col] = v;
        } else {
            int gr = m0 + row, gc = n0 + col;
            int rowtile = gr >> 4, l16p = gr & 15;
            int ksv = gc >> 5, quadp = (gc >> 3) & 3, ep = gc & 7;
            int lanep = quadp * 16 + l16p;
            Cb[((size_t)(rowtile * (ldc >> 5) + ksv) * 64 + lanep) * 8 + ep] = f2bf(v);
        }
    }
}

// ---------------------------------------------------------------- fused x1-build + pool GEMM + max_j (R15 M-split)
__global__ __launch_bounds__(512) void pool_fused(
    const float* __restrict__ Hpartf, const float* __restrict__ pos,
    const float* __restrict__ Wcx, const float* __restrict__ Wcy,
    const unsigned short* __restrict__ W2pk,
    const float* __restrict__ b2, unsigned short* __restrict__ Abf)
{
    constexpr int LDA = 72;
    constexpr int ASZ = 64 * LDA;
    __shared__ __align__(16) unsigned short As[2 * ASZ];
    const int tid = threadIdx.x;
    const int lane = tid & 63, w = tid >> 6;
    const int quad = lane >> 4, l16 = lane & 15;
    const int n_tile = blockIdx.x, m_tile2 = blockIdx.y;
    const int g = m_tile2 >> 4, iq2 = m_tile2 & 15;
    const int n0 = n_tile * 512;

    const int brow = tid >> 3;
    const int k8 = (tid & 7) * 8;
    const int bi = iq2 * 2 + (brow >> 5), bj = brow & 31;
    const float rx = pos[(g * GSZ + bj) * 2 + 0] - pos[(g * GSZ + bi) * 2 + 0];
    const float ry = pos[(g * GSZ + bj) * 2 + 1] - pos[(g * GSZ + bi) * 2 + 1];
    const float* hrow = &Hpartf[(size_t)(g * GSZ + bj) * PRE];

    auto BUILD = [&](int k0i, unsigned short* dst) {
        const int k0 = k0i * 64;
        const float* hp = hrow + k0 + k8;
        const float* wx = Wcx + k0 + k8;
        const float* wy = Wcy + k0 + k8;
        float4 ha = *(const float4*)hp, hb = *(const float4*)(hp + 4);
        float4 xa = *(const float4*)wx, xb = *(const float4*)(wx + 4);
        float4 ya = *(const float4*)wy, yb = *(const float4*)(wy + 4);
        bf8pack o;
        o.s[0] = f2bf(fmaxf(ha.x + rx * xa.x + ry * ya.x, 0.f));
        o.s[1] = f2bf(fmaxf(ha.y + rx * xa.y + ry * ya.y, 0.f));
        o.s[2] = f2bf(fmaxf(ha.z + rx * xa.z + ry * ya.z, 0.f));
        o.s[3] = f2bf(fmaxf(ha.w + rx * xa.w + ry * ya.w, 0.f));
        o.s[4] = f2bf(fmaxf(hb.x + rx * xb.x + ry * yb.x, 0.f));
        o.s[5] = f2bf(fmaxf(hb.y + rx * xb.y + ry * yb.y, 0.f));
        o.s[6] = f2bf(fmaxf(hb.z + rx * xb.z + ry * yb.z, 0.f));
        o.s[7] = f2bf(fmaxf(hb.w + rx * xb.w + ry * yb.w, 0.f));
        *(uint4*)&dst[brow * LDA + k8] = o.v;
    };

    f32x4 acc[4][4];
#pragma unroll
    for (int mt = 0; mt < 4; ++mt)
#pragma unroll
        for (int nt = 0; nt < 4; ++nt) acc[mt][nt] = (f32x4)0.f;

    BUILD(0, As);
    for (int k0i = 0; k0i < 8; ++k0i) {
        unsigned short* cur = As + (k0i & 1) * ASZ;
        __syncthreads();
        __builtin_amdgcn_s_setprio(1);
#pragma unroll
        for (int ks = 0; ks < 2; ++ks) {
            bf16x8 bfr[4];
#pragma unroll
            for (int nt = 0; nt < 4; ++nt) {
                int cg = n_tile * 32 + w * 4 + nt;
                int ksg = k0i * 2 + ks;
                bfr[nt] = *(const bf16x8*)&W2pk[((size_t)(cg * 16 + ksg) * 64 + lane) * 8];
            }
#pragma unroll
            for (int mt = 0; mt < 4; ++mt) {
                bf16x8 af = *(const bf16x8*)&cur[(mt * 16 + l16) * LDA + ks * 32 + quad * 8];
#pragma unroll
                for (int nt = 0; nt < 4; ++nt)
                    acc[mt][nt] = __builtin_amdgcn_mfma_f32_16x16x32_bf16(af, bfr[nt], acc[mt][nt], 0, 0, 0);
            }
        }
        __builtin_amdgcn_s_setprio(0);
        if (k0i < 7) BUILD(k0i + 1, As + ((k0i + 1) & 1) * ASZ);
    }

#pragma unroll
    for (int il = 0; il < 2; ++il)
#pragma unroll
    for (int nt = 0; nt < 4; ++nt) {
        float u = -1e30f;
#pragma unroll
        for (int p = 0; p < 2; ++p)
#pragma unroll
            for (int r = 0; r < 4; ++r) u = fmaxf(u, acc[il * 2 + p][nt][r]);
        u = fmaxf(u, __shfl_xor(u, 16));
        u = fmaxf(u, __shfl_xor(u, 32));
        if (lane < 16) {
            int col = n0 + w * 64 + nt * 16 + l16;
            int gu = m_tile2 * 2 + il;
            Abf[(size_t)gu * AK + H + col] = f2bf(fmaxf(u + b2[col], 0.f));
        }
    }
}

// ---------------------------------------------------------------- launch
extern "C" void kernel_launch(void* const* d_in, const int* in_sizes, int n_in,
                              void* d_out, int out_size, void* d_ws, size_t ws_size,
                              hipStream_t stream)
{
    const float* last_pos     = (const float*)d_in[0];
    const float* last_pos_rel = (const float*)d_in[1];
    const float* hh           = (const float*)d_in[2];
    const float* ch           = (const float*)d_in[3];
    const float* ptr_rel      = (const float*)d_in[4];
    const float* Wih  = (const float*)d_in[6];
    const float* Whh  = (const float*)d_in[7];
    const float* bih  = (const float*)d_in[8];
    const float* bhh  = (const float*)d_in[9];
    const float* Wse  = (const float*)d_in[10];
    const float* bse  = (const float*)d_in[11];
    const float* Wpos = (const float*)d_in[12];
    const float* bpos = (const float*)d_in[13];
    const float* Wp   = (const float*)d_in[14];
    const float* bp   = (const float*)d_in[15];
    const float* W1   = (const float*)d_in[16];
    const float* b1   = (const float*)d_in[17];
    const float* W2   = (const float*)d_in[18];
    const float* b2   = (const float*)d_in[19];
    const float* Wm1  = (const float*)d_in[20];
    const float* bm1  = (const float*)d_in[21];
    const float* Wm2  = (const float*)d_in[22];
    const float* bm2  = (const float*)d_in[23];

    float* ws     = (float*)d_ws;
    unsigned short* Ahpk = (unsigned short*)ws;  // 128KB (t=0 gate-A)
    float* cbuf   = ws + BATCH * H;           // 65536
    float* pos    = cbuf + BATCH * H;         // 1024 (padded)
    float* Hpartf = pos + 1024;               // 262144
    float* Wcx    = Hpartf + BATCH * PRE;     // 512
    float* Wcy    = Wcx + PRE;                // 512
    float* biash  = Wcy + PRE;                // 512
    float* bx     = biash + PRE;              // 512
    float* Wx0    = bx + 512;                 // 512
    float* Wx1    = Wx0 + 512;                // 512
    unsigned short* ub    = (unsigned short*)(Wx1 + 512);
    unsigned short* Abf   = ub;                         // 512*1152
    unsigned short* dhpk  = Abf + (size_t)BATCH * AK;   // 512*1024 (fragment-packed)
    unsigned short* W2pk  = dhpk + (size_t)BATCH * MLPD;
    unsigned short* Wm1pk = W2pk + (size_t)BOT * PRE;
    unsigned short* Wm2pk = Wm1pk + (size_t)MLPD * AK;
    unsigned short* W1pk  = Wm2pk + (size_t)H * MLPD;   // 512*128 (packed)
    unsigned short* Whpk  = W1pk + (size_t)PRE * H;     // 512*128 (packed)

    float* out  = (float*)d_out;
    float* loss = out + SEQ * BATCH * 2;

    prep_kernel<<<(PREP_TOT + 255) / 256, 256, 0, stream>>>(
        W2, Wm1, Wm2, W1, Wp, bp, b1, ch, hh, last_pos, Wih, Whh, bih, bhh, Wse, bse,
        W2pk, Wm1pk, Wm2pk, W1pk, Wcx, Wcy, biash, cbuf, Ahpk, pos, Whpk, Wx0, Wx1, bx, loss);

    // step 0 LSTM (gate-A from prep-packed hh)
    lstm_hpart<<<BATCH / LROWS, 512, 0, stream>>>(
        last_pos_rel, ptr_rel, Whpk, Wx0, Wx1, bx, Wpos, bpos, W1pk, biash,
        Ahpk, cbuf, Abf, Hpartf, pos, out, loss);

    for (int t = 0; t < SEQ - 1; t++) {
        // pool(t): fused x1-build + GEMM + max_j — M-split, 512 blocks, 2/CU (R15)
        pool_fused<<<dim3(2, 256), 512, 0, stream>>>(Hpartf, pos, Wcx, Wcy, W2pk, b2, Abf);
        // mlp1(t): dh -> fragment-packed dhpk — R17: reverted to R15 BM=64 config
        gemm_splitk_pk<64, 32, 2, 2, 3><<<dim3(MLPD / 32, BATCH / 64), 256, 0, stream>>>(
            Abf, AK, Wm1pk, AK, bm1, nullptr, dhpk, MLPD);
        // mlp2(t) + lstm(t+1) fused — R17: reverted to R15 single-acc phase A
        mlp2_lstm<<<BATCH / LROWS, 512, 0, stream>>>(
            t + 1, dhpk, Wm2pk, bm2,
            ptr_rel + t * BATCH * 2, ptr_rel + (t + 1) * BATCH * 2,
            Whpk, Wx0, Wx1, bx, Wpos, bpos, W1pk, biash,
            cbuf, Abf, Hpartf, pos, out + (t + 1) * BATCH * 2, loss);
    }
}